// Round 11
// baseline (4892.017 us; speedup 1.0000x reference)
//
#include <hip/hip_runtime.h>
#include <hip/hip_bf16.h>
#include <cstdint>
#include <cstddef>
#include <type_traits>

#define B_ALL 256
#define T_LEN 512
#define D_INP 64
#define HD    128
#define G4    512            // 4*H
#define NC    12
#define BCH   128            // batch per chunk
#define ROWS  (BCH * T_LEN)  // 65536 rows per chunk

// ---------- helpers ----------
__device__ __forceinline__ float bf2f(unsigned short u) {
    union { unsigned int i; float f; } v; v.i = ((unsigned int)u) << 16; return v.f;
}
__device__ __forceinline__ unsigned short f2bf(float f) {
    union { float f; unsigned int i; } v; v.f = f;
    unsigned int r = v.i + 0x7FFFu + ((v.i >> 16) & 1u);  // round-nearest-even
    return (unsigned short)(r >> 16);
}
__device__ __forceinline__ float sigf(float x) { return 1.0f / (1.0f + __expf(-x)); }
__device__ __forceinline__ float tanh_f(float x) {
    float xx = fminf(15.0f, fmaxf(-15.0f, x));
    float e = __expf(2.0f * xx);
    return (e - 1.0f) / (e + 1.0f);
}

// LDS-only barrier: drains lgkmcnt but leaves global loads/stores in flight.
#define LDS_BARRIER() asm volatile("s_waitcnt lgkmcnt(0)\n\ts_barrier" ::: "memory")

using bf16x8 = __attribute__((ext_vector_type(8))) short;
using f32x4  = __attribute__((ext_vector_type(4))) float;

// XOR swizzle for [R][32] bf16 LDS tiles (64B rows).
__device__ __forceinline__ int swz(int r, int kb) {
    return (r * 64 + kb) ^ ((r & 3) << 4);
}

// ---------- W split: fp32 -> hi/lo bf16 pair (hi+lo ~ fp32 exact) ----------
__global__ __launch_bounds__(256)
void split_w(const float* __restrict__ w, unsigned short* __restrict__ hi,
             unsigned short* __restrict__ lo, int n)
{
    int i = blockIdx.x * 256 + threadIdx.x;
    if (i < n) {
        float f = w[i];
        unsigned short h = f2bf(f);
        hi[i] = h;
        lo[i] = f2bf(f - bf2f(h));
    }
}

// ---------- gates GEMM (MFMA, split-precision bf16) — unchanged from R3 ----------
template <int TERMS, typename TA>
__global__ __launch_bounds__(256)
void gates_gemm_mfma(const TA* __restrict__ A,
                     const unsigned short* __restrict__ Whi_g,
                     const unsigned short* __restrict__ Wlo_g,
                     const float* __restrict__ bias,
                     const int* __restrict__ lens,
                     unsigned short* __restrict__ out, int K)
{
    int row0 = blockIdx.x * 128;
    int col0 = blockIdx.y * 128;
    int bl = row0 >> 9;
    int t0 = row0 & (T_LEN - 1);
    if (t0 >= lens[bl]) return;

    __shared__ __align__(16) char smem[TERMS == 3 ? 32768 : 24576];
    char* sAhi = smem;                 // [128][32] bf16, swizzled
    char* sWhi = smem + 8192;
    char* sWlo = smem + 16384;
    char* sAlo = (TERMS == 3) ? smem + 24576 : smem;

    int tid = threadIdx.x;
    int l   = tid & 63;
    int w   = tid >> 6;
    int wr  = (w >> 1) * 64;
    int wc  = (w & 1) * 64;

    f32x4 acc[4][4];
#pragma unroll
    for (int mi = 0; mi < 4; ++mi)
#pragma unroll
        for (int ni = 0; ni < 4; ++ni) acc[mi][ni] = (f32x4){0.f, 0.f, 0.f, 0.f};

    int fr = l & 15;
    int fk = (l >> 4) * 16;

    for (int kt = 0; kt < K; kt += 32) {
#pragma unroll
        for (int q = 0; q < 2; ++q) {
            int c = tid + 256 * q;
            int r = c >> 2, kc = c & 3;
            size_t gi = (size_t)(col0 + r) * K + kt + kc * 8;
            *(uint4*)(sWhi + swz(r, kc * 16)) = *(const uint4*)&Whi_g[gi];
            *(uint4*)(sWlo + swz(r, kc * 16)) = *(const uint4*)&Wlo_g[gi];
        }
        if constexpr (std::is_same<TA, unsigned short>::value) {
#pragma unroll
            for (int q = 0; q < 2; ++q) {
                int c = tid + 256 * q;
                int r = c >> 2, kc = c & 3;
                *(uint4*)(sAhi + swz(r, kc * 16)) =
                    *(const uint4*)&A[(size_t)(row0 + r) * K + kt + kc * 8];
            }
        } else {
#pragma unroll
            for (int q = 0; q < 4; ++q) {
                int c = tid + 256 * q;
                int r = c >> 3, kc = c & 7;
                float4 f = *(const float4*)&A[(size_t)(row0 + r) * K + kt + kc * 4];
                ushort4 h, lo;
                h.x = f2bf(f.x); lo.x = f2bf(f.x - bf2f(h.x));
                h.y = f2bf(f.y); lo.y = f2bf(f.y - bf2f(h.y));
                h.z = f2bf(f.z); lo.z = f2bf(f.z - bf2f(h.z));
                h.w = f2bf(f.w); lo.w = f2bf(f.w - bf2f(h.w));
                *(ushort4*)(sAhi + swz(r, kc * 8)) = h;
                *(ushort4*)(sAlo + swz(r, kc * 8)) = lo;
            }
        }
        __syncthreads();

        bf16x8 ah[4], al[4], bh[4], bl4[4];
#pragma unroll
        for (int mi = 0; mi < 4; ++mi) {
            int off = swz(wr + mi * 16 + fr, fk);
            ah[mi] = *(const bf16x8*)(sAhi + off);
            if (TERMS == 3) al[mi] = *(const bf16x8*)(sAlo + off);
        }
#pragma unroll
        for (int ni = 0; ni < 4; ++ni) {
            int off = swz(wc + ni * 16 + fr, fk);
            bh[ni]  = *(const bf16x8*)(sWhi + off);
            bl4[ni] = *(const bf16x8*)(sWlo + off);
        }
#pragma unroll
        for (int mi = 0; mi < 4; ++mi)
#pragma unroll
            for (int ni = 0; ni < 4; ++ni) {
                acc[mi][ni] = __builtin_amdgcn_mfma_f32_16x16x32_bf16(
                    ah[mi], bh[ni], acc[mi][ni], 0, 0, 0);
                acc[mi][ni] = __builtin_amdgcn_mfma_f32_16x16x32_bf16(
                    ah[mi], bl4[ni], acc[mi][ni], 0, 0, 0);
                if (TERMS == 3)
                    acc[mi][ni] = __builtin_amdgcn_mfma_f32_16x16x32_bf16(
                        al[mi], bh[ni], acc[mi][ni], 0, 0, 0);
            }
        __syncthreads();
    }

    int r4 = (l >> 4) * 4;
#pragma unroll
    for (int ni = 0; ni < 4; ++ni) {
        int col = col0 + wc + ni * 16 + fr;
        float bj = bias[col];
#pragma unroll
        for (int mi = 0; mi < 4; ++mi) {
            int row = row0 + wr + mi * 16 + r4;
            f32x4 v = acc[mi][ni];
#pragma unroll
            for (int r = 0; r < 4; ++r)
                out[(size_t)(row + r) * 1024 + col] = f2bf(v[r] + bj);
        }
    }
}

// ---------- LSTM recurrence (R11: MFMA-batched, 16 elements/block) ----------
// Root cause of the ~2400 cy/step floor (R0-R10): the compiler streams the
// per-thread weight array from L2 every timestep (256 KB/CU/step ~ 1900 cy;
// invisible to FETCH_SIZE since Whh fits in the 4 MB L2). Fix: batch 16 same-
// dir elements per block and compute G(512x16) = Whh(512x128) @ H(128x16) on
// the MATRIX pipe with split-precision bf16 (Whi*hhi + Whi*hlo + Wlo*hhi,
// err ~2^-17 — the scheme already proven in gates_gemm_mfma). Weights live as
// 16 bf16x8 A-fragments (64 VGPR/lane), pinned register-resident by ONE
// 16-operand "+v" asm per step (all simultaneously live + asm-redefined ->
// cannot be rematerialized from memory; R10's split pins allowed reloads
// between asms). h: bf16 hi/lo in LDS [16][136] (pad -> 2-way reads, free).
// G: [512][17] fp32. Nonlin: 2 (j,b) pairs/thread, c in regs, length-masked.
// Fragment mappings copied from gates_gemm_mfma (A: row=l&15,k=(l>>4)*8;
// B: col=l&15; C: col=l&15,row=(l>>4)*4+reg).
__global__ __launch_bounds__(1024, 1)
void lstm_rec_mfma(const unsigned short* __restrict__ xg,   // [ROWS][1024]
                   const unsigned short* __restrict__ Whi,  // [2][512][128] bf16
                   const unsigned short* __restrict__ Wlo,
                   const int* __restrict__ lens,            // chunk-offset
                   unsigned short* __restrict__ hs,         // [ROWS][256] or null
                   float* __restrict__ hTf, float* __restrict__ hTb,
                   int bOff)
{
    int dir = blockIdx.x >> 3;      // 8 groups per dir
    int grp = blockIdx.x & 7;       // group of 16 batch elements
    int tid = threadIdx.x;
    int wv  = tid >> 6;             // wave 0..15: owns G rows [32wv, 32wv+32)
    int l   = tid & 63;
    int fr  = l & 15;               // frag row (A) / col=b (B,C)
    int fk  = (l >> 4) * 8;         // frag k-offset (bf16 elems)

    __shared__ float G[G4][17];                 // gate pre-activations
    __shared__ unsigned short hHi[16][136];     // h bf16 hi, padded
    __shared__ unsigned short hLo[16][136];     // h bf16 lo

    // nonlin ownership: pairs (j, bb) and (j, bb+8)
    int j   = tid & 127;
    int bb  = tid >> 7;             // 0..7
    int bl0 = grp * 16 + bb;
    int bl1 = bl0 + 8;
    int L0  = lens[bl0];
    int L1  = lens[bl1];
    int Lmax = 0;
#pragma unroll
    for (int i = 0; i < 16; ++i) Lmax = max(Lmax, lens[grp * 16 + i]);

    // ---- A-fragments: Whh rows [wv*32, wv*32+32), hi+lo, loaded once ----
    const unsigned short* Ah = Whi + (size_t)dir * G4 * HD;
    const unsigned short* Al = Wlo + (size_t)dir * G4 * HD;
    bf16x8 a_hi[2][4], a_lo[2][4];
#pragma unroll
    for (int mi = 0; mi < 2; ++mi)
#pragma unroll
        for (int kt = 0; kt < 4; ++kt) {
            size_t a = (size_t)(wv * 32 + mi * 16 + fr) * HD + kt * 32 + fk;
            a_hi[mi][kt] = *(const bf16x8*)&Ah[a];
            a_lo[mi][kt] = *(const bf16x8*)&Al[a];
        }

    // ---- init h = 0 ----
    for (int i = tid; i < 16 * 136; i += 1024) {
        (&hHi[0][0])[i] = 0;
        (&hLo[0][0])[i] = 0;
    }
    float c0 = 0.f, c1 = 0.f, h0keep = 0.f, h1keep = 0.f;
    __syncthreads();

    for (int t = 0; t < Lmax; ++t) {
        // pin ALL A-frags simultaneously (asm-redefined -> must loop-carry)
        asm volatile("" :
            "+v"(a_hi[0][0]), "+v"(a_hi[0][1]), "+v"(a_hi[0][2]), "+v"(a_hi[0][3]),
            "+v"(a_hi[1][0]), "+v"(a_hi[1][1]), "+v"(a_hi[1][2]), "+v"(a_hi[1][3]),
            "+v"(a_lo[0][0]), "+v"(a_lo[0][1]), "+v"(a_lo[0][2]), "+v"(a_lo[0][3]),
            "+v"(a_lo[1][0]), "+v"(a_lo[1][1]), "+v"(a_lo[1][2]), "+v"(a_lo[1][3]));

        // ---- MFMA phase: G = Whh @ H (3-term split precision) ----
        f32x4 acc0 = (f32x4){0.f, 0.f, 0.f, 0.f};
        f32x4 acc1 = (f32x4){0.f, 0.f, 0.f, 0.f};
#pragma unroll
        for (int kt = 0; kt < 4; ++kt) {
            bf16x8 bhi = *(const bf16x8*)&hHi[fr][kt * 32 + fk];
            bf16x8 blo = *(const bf16x8*)&hLo[fr][kt * 32 + fk];
            acc0 = __builtin_amdgcn_mfma_f32_16x16x32_bf16(a_hi[0][kt], bhi, acc0, 0, 0, 0);
            acc0 = __builtin_amdgcn_mfma_f32_16x16x32_bf16(a_hi[0][kt], blo, acc0, 0, 0, 0);
            acc0 = __builtin_amdgcn_mfma_f32_16x16x32_bf16(a_lo[0][kt], bhi, acc0, 0, 0, 0);
            acc1 = __builtin_amdgcn_mfma_f32_16x16x32_bf16(a_hi[1][kt], bhi, acc1, 0, 0, 0);
            acc1 = __builtin_amdgcn_mfma_f32_16x16x32_bf16(a_hi[1][kt], blo, acc1, 0, 0, 0);
            acc1 = __builtin_amdgcn_mfma_f32_16x16x32_bf16(a_lo[1][kt], bhi, acc1, 0, 0, 0);
        }
        // write G: C layout col=l&15, row=(l>>4)*4+r
        int r4 = (l >> 4) * 4;
#pragma unroll
        for (int r = 0; r < 4; ++r) {
            G[wv * 32 + r4 + r][fr]      = acc0[r];
            G[wv * 32 + 16 + r4 + r][fr] = acc1[r];
        }
        LDS_BARRIER();

        // ---- nonlinearity: 2 (j,b) pairs per thread ----
        {
            bool v = (t < L0);
            int tt = dir ? (L0 - 1 - t) : t;
            if (!v) tt = 0;
            const unsigned short* p = xg + (size_t)(bl0 * T_LEN + tt) * 1024 + dir * G4;
            float gi = G[j][bb]       + bf2f(p[j]);
            float gf = G[j + 128][bb] + bf2f(p[j + 128]);
            float gg = G[j + 256][bb] + bf2f(p[j + 256]);
            float go = G[j + 384][bb] + bf2f(p[j + 384]);
            if (v) {
                float I = sigf(gi), F = sigf(gf), Gg = tanh_f(gg), O = sigf(go);
                c0 = F * c0 + I * Gg;
                float hn = O * tanh_f(c0);
                h0keep = hn;
                unsigned short hh = f2bf(hn);
                hHi[bb][j] = hh;
                hLo[bb][j] = f2bf(hn - bf2f(hh));
                if (hs) hs[(size_t)(bl0 * T_LEN + tt) * 256 + dir * HD + j] = hh;
            }
        }
        {
            bool v = (t < L1);
            int tt = dir ? (L1 - 1 - t) : t;
            if (!v) tt = 0;
            const unsigned short* p = xg + (size_t)(bl1 * T_LEN + tt) * 1024 + dir * G4;
            float gi = G[j][bb + 8]       + bf2f(p[j]);
            float gf = G[j + 128][bb + 8] + bf2f(p[j + 128]);
            float gg = G[j + 256][bb + 8] + bf2f(p[j + 256]);
            float go = G[j + 384][bb + 8] + bf2f(p[j + 384]);
            if (v) {
                float I = sigf(gi), F = sigf(gf), Gg = tanh_f(gg), O = sigf(go);
                c1 = F * c1 + I * Gg;
                float hn = O * tanh_f(c1);
                h1keep = hn;
                unsigned short hh = f2bf(hn);
                hHi[bb + 8][j] = hh;
                hLo[bb + 8][j] = f2bf(hn - bf2f(hh));
                if (hs) hs[(size_t)(bl1 * T_LEN + tt) * 256 + dir * HD + j] = hh;
            }
        }
        LDS_BARRIER();
    }

    if (hTf) {
        float* dst = dir ? hTb : hTf;
        dst[(size_t)(bOff + bl0) * HD + j] = h0keep;
        dst[(size_t)(bOff + bl1) * HD + j] = h1keep;
    }
}

// ---------- final FC + log_softmax ----------
__global__ __launch_bounds__(256)
void fc_lsm(const float* __restrict__ hTf, const float* __restrict__ hTb,
            const float* __restrict__ Wfc, const float* __restrict__ bfc,
            float* __restrict__ out)
{
    int b = threadIdx.x;
    const float* hb = hTb + (size_t)b * HD;
    const float* hf = hTf + (size_t)b * HD;
    float l[NC];
#pragma unroll
    for (int cc = 0; cc < NC; ++cc) {
        const float* wr = Wfc + cc * 256;
        float acc = bfc[cc];
        for (int k = 0; k < HD; k += 4) {
            acc += hb[k] * wr[k] + hb[k + 1] * wr[k + 1]
                 + hb[k + 2] * wr[k + 2] + hb[k + 3] * wr[k + 3];
            acc += hf[k] * wr[128 + k] + hf[k + 1] * wr[128 + k + 1]
                 + hf[k + 2] * wr[128 + k + 2] + hf[k + 3] * wr[128 + k + 3];
        }
        l[cc] = acc;
    }
    float m = l[0];
#pragma unroll
    for (int cc = 1; cc < NC; ++cc) m = fmaxf(m, l[cc]);
    float s = 0.0f;
#pragma unroll
    for (int cc = 0; cc < NC; ++cc) s += __expf(l[cc] - m);
    float lg = m + logf(s);
#pragma unroll
    for (int cc = 0; cc < NC; ++cc) out[(size_t)b * NC + cc] = l[cc] - lg;
}

extern "C" void kernel_launch(void* const* d_in, const int* in_sizes, int n_in,
                              void* d_out, int out_size, void* d_ws, size_t ws_size,
                              hipStream_t stream)
{
    const float* X    = (const float*)d_in[0];
    const int*   len  = (const int*)d_in[1];
    const float* Wih0 = (const float*)d_in[2];   // (2,512,64)  -> (1024,64)
    const float* Whh0 = (const float*)d_in[3];   // (2,512,128)
    const float* b0   = (const float*)d_in[4];   // (2,512) -> (1024)
    const float* Wih1 = (const float*)d_in[5];   // (2,512,256) -> (1024,256)
    const float* Whh1 = (const float*)d_in[6];
    const float* b1   = (const float*)d_in[7];
    const float* Wfc  = (const float*)d_in[8];   // (12,256)
    const float* bfc  = (const float*)d_in[9];   // (12)
    float* out = (float*)d_out;

    char* ws = (char*)d_ws;
    size_t off = 0;
    unsigned short* xg = (unsigned short*)(ws + off); off += (size_t)ROWS * 1024 * 2;
    unsigned short* h1 = (unsigned short*)(ws + off); off += (size_t)ROWS * 256 * 2;
    float* hTf = (float*)(ws + off); off += (size_t)B_ALL * HD * 4;
    float* hTb = (float*)(ws + off); off += (size_t)B_ALL * HD * 4;
    unsigned short* W0hi = (unsigned short*)(ws + off); off += 1024 * 64 * 2;
    unsigned short* W0lo = (unsigned short*)(ws + off); off += 1024 * 64 * 2;
    unsigned short* W1hi = (unsigned short*)(ws + off); off += 1024 * 256 * 2;
    unsigned short* W1lo = (unsigned short*)(ws + off); off += 1024 * 256 * 2;
    unsigned short* R0hi = (unsigned short*)(ws + off); off += 1024 * 128 * 2;  // Whh0 split
    unsigned short* R0lo = (unsigned short*)(ws + off); off += 1024 * 128 * 2;
    unsigned short* R1hi = (unsigned short*)(ws + off); off += 1024 * 128 * 2;  // Whh1 split
    unsigned short* R1lo = (unsigned short*)(ws + off); off += 1024 * 128 * 2;

    split_w<<<(1024 * 64 + 255) / 256, 256, 0, stream>>>(Wih0, W0hi, W0lo, 1024 * 64);
    split_w<<<(1024 * 256 + 255) / 256, 256, 0, stream>>>(Wih1, W1hi, W1lo, 1024 * 256);
    split_w<<<(1024 * 128 + 255) / 256, 256, 0, stream>>>(Whh0, R0hi, R0lo, 1024 * 128);
    split_w<<<(1024 * 128 + 255) / 256, 256, 0, stream>>>(Whh1, R1hi, R1lo, 1024 * 128);

    for (int ch = 0; ch < 2; ++ch) {
        const int* lc = len + ch * BCH;
        const float* Xc = X + (size_t)ch * BCH * T_LEN * D_INP;

        gates_gemm_mfma<3, float><<<dim3(ROWS / 128, 8), 256, 0, stream>>>(
            Xc, W0hi, W0lo, b0, lc, xg, D_INP);
        lstm_rec_mfma<<<16, 1024, 0, stream>>>(xg, R0hi, R0lo, lc, h1,
                                               nullptr, nullptr, 0);
        gates_gemm_mfma<2, unsigned short><<<dim3(ROWS / 128, 8), 256, 0, stream>>>(
            h1, W1hi, W1lo, b1, lc, xg, 2 * HD);
        lstm_rec_mfma<<<16, 1024, 0, stream>>>(xg, R1hi, R1lo, lc, nullptr,
                                               hTf, hTb, ch * BCH);
    }
    fc_lsm<<<1, 256, 0, stream>>>(hTf, hTb, Wfc, bfc, out);
}